// Round 1
// baseline (9344.167 us; speedup 1.0000x reference)
//
#include <hip/hip_runtime.h>

#define SLEN 256
#define BATCH 8

__device__ __forceinline__ float waveReduceMax(float v) {
  #pragma unroll
  for (int off = 32; off > 0; off >>= 1)
    v = fmaxf(v, __shfl_xor(v, off, 64));
  return v;
}
__device__ __forceinline__ float waveReduceSum(float v) {
  #pragma unroll
  for (int off = 32; off > 0; off >>= 1)
    v += __shfl_xor(v, off, 64);
  return v;
}

// One block per batch element. Inside (forward) then outside (backward) with
// __syncthreads between anti-diagonals. USE_T: keep a transposed copy of s so
// the inner reduction reads two contiguous rows (coalesced).
template <bool USE_T>
__global__ __launch_bounds__(1024) void cyk_inside_outside(
    const float* __restrict__ scores, float* __restrict__ out,
    float* __restrict__ ws) {
  const int b = blockIdx.x;
  const int tid = threadIdx.x;
  const int lane = tid & 63;
  const int wave = tid >> 6;
  const int nwaves = blockDim.x >> 6;  // 16

  const float* sc = scores + (size_t)b * SLEN * SLEN;
  float* g = out + (size_t)b * SLEN * SLEN;          // gradient accumulator == output
  float* s = ws + (size_t)b * SLEN * SLEN;           // inside scores
  float* sT = ws + (size_t)(BATCH + b) * SLEN * SLEN;  // transpose (if USE_T)

  // ---- width 1: s[i,i+1] = scores[i,i+1] ----
  for (int i = tid; i < SLEN - 1; i += blockDim.x) {
    float v = sc[i * SLEN + i + 1];
    s[i * SLEN + i + 1] = v;
    if (USE_T) sT[(i + 1) * SLEN + i] = v;
  }
  __syncthreads();

  // ---- inside: widths 2..S-1 ----
  for (int w = 2; w < SLEN; ++w) {
    const int cells = SLEN - w;
    for (int c = wave; c < cells; c += nwaves) {
      const int i = c, j = i + w;
      const float* srow = s + i * SLEN;
      float mx = -INFINITY;
      for (int k = i + 1 + lane; k < j; k += 64) {
        float r = USE_T ? sT[j * SLEN + k] : s[k * SLEN + j];
        mx = fmaxf(mx, srow[k] + r);
      }
      mx = waveReduceMax(mx);
      float sum = 0.f;
      for (int k = i + 1 + lane; k < j; k += 64) {
        float r = USE_T ? sT[j * SLEN + k] : s[k * SLEN + j];
        sum += __expf(srow[k] + r - mx);
      }
      sum = waveReduceSum(sum);
      if (lane == 0) {
        float val = sc[i * SLEN + j] + mx + __logf(sum);
        s[i * SLEN + j] = val;
        if (USE_T) sT[j * SLEN + i] = val;
      }
    }
    __syncthreads();
  }

  // ---- outside: g zeroed by memset; root marginal = 1 ----
  if (tid == 0) g[0 * SLEN + (SLEN - 1)] = 1.0f;
  __syncthreads();

  for (int w = SLEN - 1; w >= 2; --w) {
    const int cells = SLEN - w;
    for (int c = wave; c < cells; c += nwaves) {
      const int i = c, j = i + w;
      float gij = g[i * SLEN + j];  // finalized: parents have width > w
      if (gij == 0.0f) continue;
      const float lse = s[i * SLEN + j] - sc[i * SLEN + j];
      const float* srow = s + i * SLEN;
      for (int k = i + 1 + lane; k < j; k += 64) {
        float r = USE_T ? sT[j * SLEN + k] : s[k * SLEN + j];
        float contrib = gij * __expf(srow[k] + r - lse);
        atomicAdd(&g[i * SLEN + k], contrib);   // left child
        atomicAdd(&g[k * SLEN + j], contrib);   // right child
      }
    }
    __syncthreads();
  }
}

extern "C" void kernel_launch(void* const* d_in, const int* in_sizes, int n_in,
                              void* d_out, int out_size, void* d_ws, size_t ws_size,
                              hipStream_t stream) {
  const float* scores = (const float*)d_in[0];
  // d_in[1] = mask: triu(k=1) broadcast -> lens == S-1 always; unused.
  float* out = (float*)d_out;
  float* ws = (float*)d_ws;

  const size_t grad_bytes = (size_t)BATCH * SLEN * SLEN * sizeof(float);
  hipMemsetAsync(d_out, 0, grad_bytes, stream);  // accumulator + zeros below diag

  const size_t need_t = 2 * grad_bytes;  // s + sT
  if (ws_size >= need_t) {
    cyk_inside_outside<true><<<BATCH, 1024, 0, stream>>>(scores, out, ws);
  } else {
    cyk_inside_outside<false><<<BATCH, 1024, 0, stream>>>(scores, out, ws);
  }
}

// Round 2
// 4036.190 us; speedup vs baseline: 2.3151x; 2.3151x over previous
//
#include <hip/hip_runtime.h>

#define SL 256
#define BATCH 8
#define NT 1024

// One block per batch element. Inside (widths ascending) then outside
// (widths descending, GATHER form -> no atomics). Per diagonal, a group of
// G lanes owns one cell; G adapts so ngroups >= cells (G in [4,64]).
// Transposed copies sT/lT/gT make every inner-loop read a coalesced row.
template <bool UT>
__global__ __launch_bounds__(NT) void cyk_io(
    const float* __restrict__ scores, float* __restrict__ out,
    float* __restrict__ ws) {
  const int b = blockIdx.x;
  const int tid = threadIdx.x;
  const size_t P = (size_t)SL * SL;

  const float* sc = scores + (size_t)b * P;
  float* g  = out + (size_t)b * P;                    // marginals accumulator
  float* s  = ws + (size_t)b * P;                     // inside scores
  float* sT = ws + (size_t)(BATCH + b) * P;           // s transposed
  float* l  = ws + (size_t)(2 * BATCH + b) * P;       // lse = s - sc
  float* lT = ws + (size_t)(3 * BATCH + b) * P;       // lse transposed
  float* gT = ws + (size_t)(4 * BATCH + b) * P;       // g transposed

  // ---- width 1: s = scores, lse = 0 ----
  for (int i = tid; i < SL - 1; i += NT) {
    float v = sc[i * SL + i + 1];
    s[i * SL + i + 1] = v;
    l[i * SL + i + 1] = 0.f;
    if (UT) { sT[(i + 1) * SL + i] = v; lT[(i + 1) * SL + i] = 0.f; }
  }
  __syncthreads();

  // ---- inside: widths 2..SL-1 ----
  for (int w = 2; w < SL; ++w) {
    const int cells = SL - w;
    int G = NT / cells;
    G = (G >= 64) ? 64 : (1 << (31 - __clz(G)));      // pow2 floor, <=64
    const int lg = 31 - __clz(G);
    const int c = tid >> lg;
    const int lig = tid & (G - 1);
    if (c < cells) {
      const int i = c, j = i + w;
      const float* srow = s + i * SL;
      float m = -INFINITY;
      if (UT) {
        const float* scol = sT + j * SL;
        for (int k = i + 1 + lig; k < j; k += G) m = fmaxf(m, srow[k] + scol[k]);
      } else {
        for (int k = i + 1 + lig; k < j; k += G) m = fmaxf(m, srow[k] + s[k * SL + j]);
      }
      #pragma unroll
      for (int o = 32; o; o >>= 1)
        if (o < G) m = fmaxf(m, __shfl_xor(m, o, 64));
      float sum = 0.f;
      if (UT) {
        const float* scol = sT + j * SL;
        for (int k = i + 1 + lig; k < j; k += G) sum += __expf(srow[k] + scol[k] - m);
      } else {
        for (int k = i + 1 + lig; k < j; k += G) sum += __expf(srow[k] + s[k * SL + j] - m);
      }
      #pragma unroll
      for (int o = 32; o; o >>= 1)
        if (o < G) sum += __shfl_xor(sum, o, 64);
      if (lig == 0) {
        const float lse = m + __logf(sum);
        const float val = sc[i * SL + j] + lse;
        s[i * SL + j] = val;
        l[i * SL + j] = lse;
        if (UT) { sT[j * SL + i] = val; lT[j * SL + i] = lse; }
      }
    }
    __syncthreads();
  }

  // ---- outside (gather): root marginal = 1 ----
  if (tid == 0) {
    g[0 * SL + (SL - 1)] = 1.0f;
    if (UT) gT[(SL - 1) * SL + 0] = 1.0f;
  }
  __syncthreads();

  for (int w = SL - 2; w >= 1; --w) {
    const int cells = SL - w;
    int G = NT / cells;
    G = (G >= 64) ? 64 : (1 << (31 - __clz(G)));
    const int lg = 31 - __clz(G);
    const int c = tid >> lg;
    const int lig = tid & (G - 1);
    if (c < cells) {
      const int p = c, q = p + w;
      const float spq = s[p * SL + q];
      const int TR = SL - 1 - q;   // right-parent terms (p, j>q)
      const int T = TR + p;        // + left-parent terms (i<p, q)
      float acc = 0.f;
      for (int t = lig; t < T; t += G) {
        if (t < TR) {
          const int j = q + 1 + t;
          // parent (p,j), split q: exponent <= 0 by construction
          acc += g[p * SL + j] * __expf(spq + s[q * SL + j] - l[p * SL + j]);
        } else {
          const int i = t - TR;
          // parent (i,q), split p
          if (UT)
            acc += gT[q * SL + i] * __expf(sT[p * SL + i] + spq - lT[q * SL + i]);
          else
            acc += g[i * SL + q] * __expf(s[i * SL + p] + spq - l[i * SL + q]);
        }
      }
      #pragma unroll
      for (int o = 32; o; o >>= 1)
        if (o < G) acc += __shfl_xor(acc, o, 64);
      if (lig == 0) {
        g[p * SL + q] = acc;
        if (UT) gT[q * SL + p] = acc;
      }
    }
    __syncthreads();
  }
}

extern "C" void kernel_launch(void* const* d_in, const int* in_sizes, int n_in,
                              void* d_out, int out_size, void* d_ws, size_t ws_size,
                              hipStream_t stream) {
  const float* scores = (const float*)d_in[0];
  // d_in[1] = mask: triu(k=1) broadcast -> lens == SL-1 always; unused.
  float* out = (float*)d_out;
  float* ws = (float*)d_ws;

  const size_t arr_bytes = (size_t)BATCH * SL * SL * sizeof(float);  // 2 MB
  hipMemsetAsync(d_out, 0, arr_bytes, stream);

  if (ws_size >= 5 * arr_bytes)
    cyk_io<true><<<BATCH, NT, 0, stream>>>(scores, out, ws);
  else
    cyk_io<false><<<BATCH, NT, 0, stream>>>(scores, out, ws);
}

// Round 3
// 2311.754 us; speedup vs baseline: 4.0420x; 1.7459x over previous
//
#include <hip/hip_runtime.h>

#define SL 256
#define BATCH 8
#define NT 1024
#define TRI ((SL * (SL - 1)) / 2)   // 32640 cells in strict upper triangle
#define LDSB (TRI * 4)              // 130560 B packed inside-score table

// packed index of cell (i,j), 0<=i<j<SL:  triRow(i) + j - i - 1
__device__ __forceinline__ int triRow(int i) { return (i * (2 * SL - 1 - i)) >> 1; }

__device__ __forceinline__ float grpMax(float v, int G) {
  #pragma unroll
  for (int o = 32; o; o >>= 1)
    if (o < G) v = fmaxf(v, __shfl_xor(v, o, 64));
  return v;
}
__device__ __forceinline__ float grpSum(float v, int G) {
  #pragma unroll
  for (int o = 32; o; o >>= 1)
    if (o < G) v += __shfl_xor(v, o, 64);
  return v;
}

// ---------------- v3: LDS-resident inside table ----------------
// One block per batch element. Packed upper-tri s in LDS; (g,lse) float2
// pairs in global ws (+ transposed copy when UT). Gather-form outside.
template <bool UT>
__global__ __launch_bounds__(NT) void cyk_lds(
    const float* __restrict__ scores, float* __restrict__ out,
    float* __restrict__ ws) {
  extern __shared__ float sh[];   // TRI floats: packed inside scores
  const int b = blockIdx.x;
  const int tid = threadIdx.x;
  const size_t P = (size_t)SL * SL;

  const float* sc = scores + (size_t)b * P;
  float* g = out + (size_t)b * P;
  float2* pr  = (float2*)ws + (size_t)b * P;            // (.x=g, .y=lse) row-major
  float2* prT = (float2*)ws + (size_t)(BATCH + b) * P;  // transposed copy (UT)

  // ---- width 1: s = scores, lse = 0 ----
  for (int i = tid; i < SL - 1; i += NT) {
    sh[triRow(i)] = sc[i * SL + i + 1];   // (i, i+1) -> offset 0 in row i
    pr[i * SL + i + 1].y = 0.f;
    if (UT) prT[(i + 1) * SL + i].y = 0.f;
  }
  __syncthreads();

  // ---- inside: widths 2..SL-1, all reads/writes of s in LDS ----
  for (int w = 2; w < SL; ++w) {
    const int cells = SL - w;
    int G = NT / cells;
    G = (G >= 64) ? 64 : (1 << (31 - __clz(G)));   // pow2, <=64
    const int lg = 31 - __clz(G);
    const int c = tid >> lg;
    const int lig = tid & (G - 1);
    if (c < cells) {
      const int i = c, j = i + w;
      const int ro = triRow(i) - i - 1;            // sh[ro+k] == s[i,k]
      float m = -INFINITY;
      for (int k = i + 1 + lig; k < j; k += G)
        m = fmaxf(m, sh[ro + k] + sh[triRow(k) + j - k - 1]);
      m = grpMax(m, G);
      float sum = 0.f;
      for (int k = i + 1 + lig; k < j; k += G)
        sum += __expf(sh[ro + k] + sh[triRow(k) + j - k - 1] - m);
      sum = grpSum(sum, G);
      if (lig == 0) {
        const float lse = m + __logf(sum);
        sh[ro + j] = sc[i * SL + j] + lse;         // s[i,j]
        pr[i * SL + j].y = lse;
        if (UT) prT[j * SL + i].y = lse;
      }
    }
    __syncthreads();
  }

  // ---- outside (gather, no atomics): root marginal = 1 ----
  if (tid == 0) {
    g[0 * SL + (SL - 1)] = 1.0f;
    pr[0 * SL + (SL - 1)].x = 1.0f;
    if (UT) prT[(SL - 1) * SL + 0].x = 1.0f;
  }
  __syncthreads();

  for (int w = SL - 2; w >= 1; --w) {
    const int cells = SL - w;
    int G = NT / cells;
    G = (G >= 64) ? 64 : (1 << (31 - __clz(G)));
    const int lg = 31 - __clz(G);
    const int c = tid >> lg;
    const int lig = tid & (G - 1);
    if (c < cells) {
      const int p = c, q = p + w;
      const float spq = sh[triRow(p) + q - p - 1];
      const int qo = triRow(q) - q - 1;            // sh[qo+j] == s[q,j]
      const int TR = SL - 1 - q;                   // right-parent terms (p,j), j>q
      const int T = TR + p;                        // + left-parent terms (i,q), i<p
      float acc = 0.f;
      for (int t = lig; t < T; t += G) {
        if (t < TR) {
          const int j = q + 1 + t;
          const float2 v = pr[p * SL + j];         // (g, lse) in one 8B load
          acc += v.x * __expf(spq + sh[qo + j] - v.y);   // exponent <= 0
        } else {
          const int i = t - TR;
          const float2 v = UT ? prT[q * SL + i] : pr[i * SL + q];
          acc += v.x * __expf(sh[triRow(i) + p - i - 1] + spq - v.y);
        }
      }
      acc = grpSum(acc, G);
      if (lig == 0) {
        g[p * SL + q] = acc;
        pr[p * SL + q].x = acc;
        if (UT) prT[q * SL + p].x = acc;
      }
    }
    __syncthreads();
  }
}

// ---------------- fallback: v2 global-memory kernel (proven) ----------------
template <bool UT>
__global__ __launch_bounds__(NT) void cyk_io(
    const float* __restrict__ scores, float* __restrict__ out,
    float* __restrict__ ws) {
  const int b = blockIdx.x;
  const int tid = threadIdx.x;
  const size_t P = (size_t)SL * SL;

  const float* sc = scores + (size_t)b * P;
  float* g  = out + (size_t)b * P;
  float* s  = ws + (size_t)b * P;
  float* sT = ws + (size_t)(BATCH + b) * P;
  float* l  = ws + (size_t)(2 * BATCH + b) * P;
  float* lT = ws + (size_t)(3 * BATCH + b) * P;
  float* gT = ws + (size_t)(4 * BATCH + b) * P;

  for (int i = tid; i < SL - 1; i += NT) {
    float v = sc[i * SL + i + 1];
    s[i * SL + i + 1] = v;
    l[i * SL + i + 1] = 0.f;
    if (UT) { sT[(i + 1) * SL + i] = v; lT[(i + 1) * SL + i] = 0.f; }
  }
  __syncthreads();

  for (int w = 2; w < SL; ++w) {
    const int cells = SL - w;
    int G = NT / cells;
    G = (G >= 64) ? 64 : (1 << (31 - __clz(G)));
    const int lg = 31 - __clz(G);
    const int c = tid >> lg;
    const int lig = tid & (G - 1);
    if (c < cells) {
      const int i = c, j = i + w;
      const float* srow = s + i * SL;
      float m = -INFINITY;
      for (int k = i + 1 + lig; k < j; k += G) {
        float r = UT ? sT[j * SL + k] : s[k * SL + j];
        m = fmaxf(m, srow[k] + r);
      }
      m = grpMax(m, G);
      float sum = 0.f;
      for (int k = i + 1 + lig; k < j; k += G) {
        float r = UT ? sT[j * SL + k] : s[k * SL + j];
        sum += __expf(srow[k] + r - m);
      }
      sum = grpSum(sum, G);
      if (lig == 0) {
        const float lse = m + __logf(sum);
        const float val = sc[i * SL + j] + lse;
        s[i * SL + j] = val;
        l[i * SL + j] = lse;
        if (UT) { sT[j * SL + i] = val; lT[j * SL + i] = lse; }
      }
    }
    __syncthreads();
  }

  if (tid == 0) {
    g[0 * SL + (SL - 1)] = 1.0f;
    if (UT) gT[(SL - 1) * SL + 0] = 1.0f;
  }
  __syncthreads();

  for (int w = SL - 2; w >= 1; --w) {
    const int cells = SL - w;
    int G = NT / cells;
    G = (G >= 64) ? 64 : (1 << (31 - __clz(G)));
    const int lg = 31 - __clz(G);
    const int c = tid >> lg;
    const int lig = tid & (G - 1);
    if (c < cells) {
      const int p = c, q = p + w;
      const float spq = s[p * SL + q];
      const int TR = SL - 1 - q;
      const int T = TR + p;
      float acc = 0.f;
      for (int t = lig; t < T; t += G) {
        if (t < TR) {
          const int j = q + 1 + t;
          acc += g[p * SL + j] * __expf(spq + s[q * SL + j] - l[p * SL + j]);
        } else {
          const int i = t - TR;
          if (UT)
            acc += gT[q * SL + i] * __expf(sT[p * SL + i] + spq - lT[q * SL + i]);
          else
            acc += g[i * SL + q] * __expf(s[i * SL + p] + spq - l[i * SL + q]);
        }
      }
      acc = grpSum(acc, G);
      if (lig == 0) {
        g[p * SL + q] = acc;
        if (UT) gT[q * SL + p] = acc;
      }
    }
    __syncthreads();
  }
}

extern "C" void kernel_launch(void* const* d_in, const int* in_sizes, int n_in,
                              void* d_out, int out_size, void* d_ws, size_t ws_size,
                              hipStream_t stream) {
  const float* scores = (const float*)d_in[0];
  // d_in[1] = mask: triu(k=1) broadcast -> lens == SL-1 always; unused.
  float* out = (float*)d_out;
  float* ws = (float*)d_ws;

  const size_t arr = (size_t)BATCH * SL * SL * sizeof(float);  // 2 MB
  hipMemsetAsync(d_out, 0, arr, stream);

  int dev = 0;
  hipGetDevice(&dev);
  int maxShm = 0;
  hipDeviceGetAttribute(&maxShm, hipDeviceAttributeMaxSharedMemoryPerBlock, dev);
  // CUDA-style opt-in for >default dynamic LDS; ignore errors (no-op on ROCm).
  (void)hipFuncSetAttribute(reinterpret_cast<const void*>(cyk_lds<true>),
                            hipFuncAttributeMaxDynamicSharedMemorySize, LDSB);
  (void)hipFuncSetAttribute(reinterpret_cast<const void*>(cyk_lds<false>),
                            hipFuncAttributeMaxDynamicSharedMemorySize, LDSB);

  if (maxShm >= LDSB && ws_size >= 4 * arr) {          // pr + prT (float2 each)
    cyk_lds<true><<<BATCH, NT, LDSB, stream>>>(scores, out, ws);
  } else if (maxShm >= LDSB && ws_size >= 2 * arr) {   // pr only
    cyk_lds<false><<<BATCH, NT, LDSB, stream>>>(scores, out, ws);
  } else if (ws_size >= 5 * arr) {
    cyk_io<true><<<BATCH, NT, 0, stream>>>(scores, out, ws);
  } else {
    cyk_io<false><<<BATCH, NT, 0, stream>>>(scores, out, ws);
  }
}

// Round 4
// 1485.367 us; speedup vs baseline: 6.2908x; 1.5564x over previous
//
#include <hip/hip_runtime.h>

#define SL 256
#define BATCH 8
#define NT 1024
#define TRI ((SL * (SL - 1)) / 2)   // 32640 floats, strict upper triangle
#define LDSB (TRI * 4)              // 130560 B
#define NEGL (-1.0e30f)

// packed index of (i,j), i<j:  triRow(i) + j - i - 1
__device__ __forceinline__ int triRow(int i) { return (i * (2 * SL - 1 - i)) >> 1; }

// ---------------- inside: widths [w0,w1), compile-time group size G ----------
// Single-pass chunked online-LSE, strength-reduced column addresses.
template <int G, bool UT>
__device__ __forceinline__ void insidePhase(
    int w0, int w1, int tid, const float* __restrict__ sc,
    float2* __restrict__ pr, float2* __restrict__ prT, float* __restrict__ sh) {
  constexpr int LG = (G == 4) ? 2 : (G == 8) ? 3 : (G == 16) ? 4 : (G == 32) ? 5 : 6;
  const int c = tid >> LG;
  const int lig = tid & (G - 1);
  for (int w = w0; w < w1; ++w) {
    if (c < SL - w) {
      const int i = c, j = i + w;
      const int ro = triRow(i) - i - 1;            // sh[ro+k] == s[i,k]
      int k = i + 1 + lig;
      const float* rp = sh + ro + k;
      int ca = triRow(k) + j - k - 1;              // sh[ca] == s[k,j]
      int cd = (G * (2 * SL - 1 - G)) / 2 - G * k - G;  // A(k+G)-A(k)
      float m = NEGL, sum = 0.f;
      while (k + 3 * G < j) {                      // 4 terms valid
        float l0 = rp[0], l1 = rp[G], l2 = rp[2 * G], l3 = rp[3 * G];
        float r0 = sh[ca];
        int ca1 = ca + cd; cd -= G * G;
        float r1 = sh[ca1];
        int ca2 = ca1 + cd; cd -= G * G;
        float r2 = sh[ca2];
        int ca3 = ca2 + cd; cd -= G * G;
        float r3 = sh[ca3];
        ca = ca3 + cd; cd -= G * G;
        rp += 4 * G; k += 4 * G;
        float t0 = l0 + r0, t1 = l1 + r1, t2 = l2 + r2, t3 = l3 + r3;
        float cm = fmaxf(fmaxf(t0, t1), fmaxf(t2, t3));
        float nm = fmaxf(m, cm);
        sum = sum * __expf(m - nm) + __expf(t0 - nm) + __expf(t1 - nm)
            + __expf(t2 - nm) + __expf(t3 - nm);
        m = nm;
      }
      for (; k < j; k += G) {
        float t = rp[0] + sh[ca];
        rp += G; ca += cd; cd -= G * G;
        float nm = fmaxf(m, t);
        sum = sum * __expf(m - nm) + __expf(t - nm);
        m = nm;
      }
      #pragma unroll
      for (int o = G >> 1; o; o >>= 1) {           // combine (m,sum) pairs
        float mo = __shfl_xor(m, o, 64);
        float so = __shfl_xor(sum, o, 64);
        float nm = fmaxf(m, mo);
        sum = sum * __expf(m - nm) + so * __expf(mo - nm);
        m = nm;
      }
      if (lig == 0) {
        const float lse = m + __logf(sum);
        sh[ro + j] = sc[i * SL + j] + lse;         // s[i,j]
        pr[i * SL + j].y = lse;
        if (UT) prT[j * SL + i].y = lse;
      }
    }
    __syncthreads();
  }
}

// ---------------- outside: widths w0 down to w1, compile-time G --------------
// Gather form; exponents <= 0 by construction (lse dominates each split term).
template <int G, bool UT>
__device__ __forceinline__ void outsidePhase(
    int w0, int w1, int tid, float* __restrict__ g,
    float2* __restrict__ pr, float2* __restrict__ prT, float* __restrict__ sh) {
  constexpr int LG = (G == 4) ? 2 : (G == 8) ? 3 : (G == 16) ? 4 : (G == 32) ? 5 : 6;
  const int c = tid >> LG;
  const int lig = tid & (G - 1);
  for (int w = w0; w >= w1; --w) {
    if (c < SL - w) {
      const int p = c, q = p + w;
      const float spq = sh[triRow(p) + q - p - 1];
      const int qo = triRow(q) - q - 1;            // sh[qo+j] == s[q,j]
      float acc = 0.f;
      {  // right parents (p,j), j>q: all-linear addresses
        int j = q + 1 + lig;
        const float2* pp = pr + p * SL + j;
        const float* jp = sh + qo + j;
        while (j + 3 * G < SL) {
          float2 v0 = pp[0], v1 = pp[G], v2 = pp[2 * G], v3 = pp[3 * G];
          float r0 = jp[0], r1 = jp[G], r2 = jp[2 * G], r3 = jp[3 * G];
          acc += v0.x * __expf(spq + r0 - v0.y);
          acc += v1.x * __expf(spq + r1 - v1.y);
          acc += v2.x * __expf(spq + r2 - v2.y);
          acc += v3.x * __expf(spq + r3 - v3.y);
          pp += 4 * G; jp += 4 * G; j += 4 * G;
        }
        for (; j < SL; j += G) {
          float2 v = pp[0];
          acc += v.x * __expf(spq + jp[0] - v.y);
          pp += G; jp += G;
        }
      }
      {  // left parents (i,q), i<p: SR'd quadratic LDS address
        constexpr int TSTEP = UT ? 1 : SL;
        int i = lig;
        int la = triRow(i) + p - i - 1;            // sh[la] == s[i,p]
        int ld = (G * (2 * SL - 1 - G)) / 2 - G * i - G;
        const float2* tp = (UT ? (prT + q * SL) : (pr + q)) + (size_t)i * TSTEP;
        while (i + 3 * G < p) {
          float2 v0 = tp[0], v1 = tp[G * TSTEP], v2 = tp[2 * G * TSTEP], v3 = tp[3 * G * TSTEP];
          float r0 = sh[la];
          int la1 = la + ld; ld -= G * G;
          float r1 = sh[la1];
          int la2 = la1 + ld; ld -= G * G;
          float r2 = sh[la2];
          int la3 = la2 + ld; ld -= G * G;
          float r3 = sh[la3];
          la = la3 + ld; ld -= G * G;
          acc += v0.x * __expf(r0 + spq - v0.y);
          acc += v1.x * __expf(r1 + spq - v1.y);
          acc += v2.x * __expf(r2 + spq - v2.y);
          acc += v3.x * __expf(r3 + spq - v3.y);
          tp += 4 * G * TSTEP; i += 4 * G;
        }
        for (; i < p; i += G) {
          float2 v = tp[0];
          acc += v.x * __expf(sh[la] + spq - v.y);
          tp += G * TSTEP; la += ld; ld -= G * G;
        }
      }
      #pragma unroll
      for (int o = G >> 1; o; o >>= 1) acc += __shfl_xor(acc, o, 64);
      if (lig == 0) {
        g[p * SL + q] = acc;
        pr[p * SL + q].x = acc;
        if (UT) prT[q * SL + p].x = acc;
      }
    }
    __syncthreads();
  }
}

// One block per batch element. Packed upper-tri inside table in LDS; (g,lse)
// float2 pairs in global ws (+ transposed copy when UT).
template <bool UT>
__global__ __launch_bounds__(NT) void cyk_lds(
    const float* __restrict__ scores, float* __restrict__ out,
    float* __restrict__ ws) {
  extern __shared__ float sh[];
  const int b = blockIdx.x;
  const int tid = threadIdx.x;
  const size_t P = (size_t)SL * SL;

  const float* sc = scores + (size_t)b * P;
  float* g = out + (size_t)b * P;
  float2* pr  = (float2*)ws + (size_t)b * P;
  float2* prT = (float2*)ws + (size_t)(BATCH + b) * P;

  // width 1: s = scores, lse = 0
  for (int i = tid; i < SL - 1; i += NT) {
    sh[triRow(i)] = sc[i * SL + i + 1];
    pr[i * SL + i + 1].y = 0.f;
    if (UT) prT[(i + 1) * SL + i].y = 0.f;
  }
  __syncthreads();

  // G(w) phases: G = pow2floor(NT/cells) clamped [4,64]
  insidePhase<4,  UT>(2,   128, tid, sc, pr, prT, sh);
  insidePhase<8,  UT>(128, 192, tid, sc, pr, prT, sh);
  insidePhase<16, UT>(192, 224, tid, sc, pr, prT, sh);
  insidePhase<32, UT>(224, 240, tid, sc, pr, prT, sh);
  insidePhase<64, UT>(240, 256, tid, sc, pr, prT, sh);

  if (tid == 0) {  // root marginal
    g[0 * SL + (SL - 1)] = 1.0f;
    pr[0 * SL + (SL - 1)].x = 1.0f;
    if (UT) prT[(SL - 1) * SL + 0].x = 1.0f;
  }
  __syncthreads();

  outsidePhase<64, UT>(SL - 2, 240, tid, g, pr, prT, sh);
  outsidePhase<32, UT>(239, 224, tid, g, pr, prT, sh);
  outsidePhase<16, UT>(223, 192, tid, g, pr, prT, sh);
  outsidePhase<8,  UT>(191, 128, tid, g, pr, prT, sh);
  outsidePhase<4,  UT>(127, 1,   tid, g, pr, prT, sh);
}

// ---------------- fallback: v2 global-memory kernel (proven) ----------------
__device__ __forceinline__ float grpMaxR(float v, int G) {
  #pragma unroll
  for (int o = 32; o; o >>= 1)
    if (o < G) v = fmaxf(v, __shfl_xor(v, o, 64));
  return v;
}
__device__ __forceinline__ float grpSumR(float v, int G) {
  #pragma unroll
  for (int o = 32; o; o >>= 1)
    if (o < G) v += __shfl_xor(v, o, 64);
  return v;
}

template <bool UT>
__global__ __launch_bounds__(NT) void cyk_io(
    const float* __restrict__ scores, float* __restrict__ out,
    float* __restrict__ ws) {
  const int b = blockIdx.x;
  const int tid = threadIdx.x;
  const size_t P = (size_t)SL * SL;
  const float* sc = scores + (size_t)b * P;
  float* g  = out + (size_t)b * P;
  float* s  = ws + (size_t)b * P;
  float* sT = ws + (size_t)(BATCH + b) * P;
  float* l  = ws + (size_t)(2 * BATCH + b) * P;
  float* lT = ws + (size_t)(3 * BATCH + b) * P;
  float* gT = ws + (size_t)(4 * BATCH + b) * P;

  for (int i = tid; i < SL - 1; i += NT) {
    float v = sc[i * SL + i + 1];
    s[i * SL + i + 1] = v;
    l[i * SL + i + 1] = 0.f;
    if (UT) { sT[(i + 1) * SL + i] = v; lT[(i + 1) * SL + i] = 0.f; }
  }
  __syncthreads();

  for (int w = 2; w < SL; ++w) {
    const int cells = SL - w;
    int G = NT / cells;
    G = (G >= 64) ? 64 : (1 << (31 - __clz(G)));
    const int lg = 31 - __clz(G);
    const int c = tid >> lg;
    const int lig = tid & (G - 1);
    if (c < cells) {
      const int i = c, j = i + w;
      const float* srow = s + i * SL;
      float m = -INFINITY;
      for (int k = i + 1 + lig; k < j; k += G) {
        float r = UT ? sT[j * SL + k] : s[k * SL + j];
        m = fmaxf(m, srow[k] + r);
      }
      m = grpMaxR(m, G);
      float sum = 0.f;
      for (int k = i + 1 + lig; k < j; k += G) {
        float r = UT ? sT[j * SL + k] : s[k * SL + j];
        sum += __expf(srow[k] + r - m);
      }
      sum = grpSumR(sum, G);
      if (lig == 0) {
        const float lse = m + __logf(sum);
        const float val = sc[i * SL + j] + lse;
        s[i * SL + j] = val;
        l[i * SL + j] = lse;
        if (UT) { sT[j * SL + i] = val; lT[j * SL + i] = lse; }
      }
    }
    __syncthreads();
  }

  if (tid == 0) {
    g[0 * SL + (SL - 1)] = 1.0f;
    if (UT) gT[(SL - 1) * SL + 0] = 1.0f;
  }
  __syncthreads();

  for (int w = SL - 2; w >= 1; --w) {
    const int cells = SL - w;
    int G = NT / cells;
    G = (G >= 64) ? 64 : (1 << (31 - __clz(G)));
    const int lg = 31 - __clz(G);
    const int c = tid >> lg;
    const int lig = tid & (G - 1);
    if (c < cells) {
      const int p = c, q = p + w;
      const float spq = s[p * SL + q];
      const int TR = SL - 1 - q;
      const int T = TR + p;
      float acc = 0.f;
      for (int t = lig; t < T; t += G) {
        if (t < TR) {
          const int j = q + 1 + t;
          acc += g[p * SL + j] * __expf(spq + s[q * SL + j] - l[p * SL + j]);
        } else {
          const int i = t - TR;
          if (UT)
            acc += gT[q * SL + i] * __expf(sT[p * SL + i] + spq - lT[q * SL + i]);
          else
            acc += g[i * SL + q] * __expf(s[i * SL + p] + spq - l[i * SL + q]);
        }
      }
      acc = grpSumR(acc, G);
      if (lig == 0) {
        g[p * SL + q] = acc;
        if (UT) gT[q * SL + p] = acc;
      }
    }
    __syncthreads();
  }
}

extern "C" void kernel_launch(void* const* d_in, const int* in_sizes, int n_in,
                              void* d_out, int out_size, void* d_ws, size_t ws_size,
                              hipStream_t stream) {
  const float* scores = (const float*)d_in[0];
  // d_in[1] = mask: triu(k=1) broadcast -> lens == SL-1 always; unused.
  float* out = (float*)d_out;
  float* ws = (float*)d_ws;

  const size_t arr = (size_t)BATCH * SL * SL * sizeof(float);  // 2 MB
  hipMemsetAsync(d_out, 0, arr, stream);

  int dev = 0;
  hipGetDevice(&dev);
  int maxShm = 0;
  hipDeviceGetAttribute(&maxShm, hipDeviceAttributeMaxSharedMemoryPerBlock, dev);
  (void)hipFuncSetAttribute(reinterpret_cast<const void*>(cyk_lds<true>),
                            hipFuncAttributeMaxDynamicSharedMemorySize, LDSB);
  (void)hipFuncSetAttribute(reinterpret_cast<const void*>(cyk_lds<false>),
                            hipFuncAttributeMaxDynamicSharedMemorySize, LDSB);

  if (maxShm >= LDSB && ws_size >= 4 * arr) {          // pr + prT (float2 each)
    cyk_lds<true><<<BATCH, NT, LDSB, stream>>>(scores, out, ws);
  } else if (maxShm >= LDSB && ws_size >= 2 * arr) {   // pr only
    cyk_lds<false><<<BATCH, NT, LDSB, stream>>>(scores, out, ws);
  } else if (ws_size >= 5 * arr) {
    cyk_io<true><<<BATCH, NT, 0, stream>>>(scores, out, ws);
  } else {
    cyk_io<false><<<BATCH, NT, 0, stream>>>(scores, out, ws);
  }
}

// Round 5
// 958.807 us; speedup vs baseline: 9.7456x; 1.5492x over previous
//
#include <hip/hip_runtime.h>

#define SL 256
#define BATCH 8
#define NT 1024
#define W0 32
#define LDSF 33152                 // padded packed triangle (floats), 16B-aligned rows
#define REDF 32
#define LDSB ((LDSF + REDF) * 4)   // 132,736 B dynamic LDS

// Row j (j in [1,255], holding cells (k,j), k=0..j-1) packed: rows j and 256-j
// share a 260-float slot; every row base is 16B-aligned.
__device__ __forceinline__ int rowOff(int j) {
  if (j <= 127) return (j - 1) * 260;
  if (j == 128) return 127 * 260;
  int jp = 256 - j;                       // 1..127
  return (jp - 1) * 260 + ((jp + 3) & ~3);
}

template <int G>
__device__ __forceinline__ float grpSum(float v) {
#pragma unroll
  for (int o = G >> 1; o; o >>= 1) v += __shfl_xor(v, o, 64);
  return v;
}

// Rescale E tables by exp(-dc*width) for all computed widths <= wcur.
__device__ void rescaleE(int tid, float dc, int wcur, float* Eg, float* sh) {
  const int lane = tid & 63, wave = tid >> 6;
  for (int j = 1 + wave; j < SL; j += 16) {
    int jlo = j - wcur; if (jlo < 0) jlo = 0;
    int base = rowOff(j);
    for (int i = jlo + lane; i < j; i += 64)
      sh[base + i] *= __expf(-dc * (float)(j - i));
  }
  for (int idx = tid; idx < SL * SL; idx += NT) {
    int i = idx >> 8, j = idx & 255;
    int wd = j - i;
    if (wd > 0 && wd <= wcur) Eg[idx] *= __expf(-dc * (float)wd);
  }
}

// Inside widths [w0,w1]: R = sum_k E[i,k]*E[k,j]; E_cell = R*exp(sc).
template <int G>
__device__ __forceinline__ void insideB(int w0, int w1, int tid,
    const float* __restrict__ sc, float* __restrict__ Eg,
    float* __restrict__ sh, float* __restrict__ red) {
  constexpr int LG = (G == 4) ? 2 : (G == 8) ? 3 : (G == 16) ? 4 : (G == 32) ? 5 : 6;
  const int c = tid >> LG, lig = tid & (G - 1);
  for (int w = w0; w <= w1; ++w) {
    const int fidx = 16 + (w & 1);        // ping-pong flag slot (race-free read)
    if (c < SL - w) {
      const int i = c, j = i + w;
      const int oj = rowOff(j);
      const float* er = Eg + i * SL;
      float a0 = 0.f, a1 = 0.f;
      for (int s4 = ((i + 1) & ~3) + 4 * lig; s4 < j; s4 += 4 * G) {
        float4 a = *(const float4*)(er + s4);          // global, coalesced b128
        float4 bv = *(const float4*)(sh + oj + s4);    // LDS, contiguous b128
        a0 = fmaf(a.x, bv.x, a0);
        a1 = fmaf(a.y, bv.y, a1);
        a0 = fmaf(a.z, bv.z, a0);
        a1 = fmaf(a.w, bv.w, a1);
      }
      float acc = grpSum<G>(a0 + a1);
      if (lig == 0) {
        float E = acc * __expf(sc[i * SL + j]);
        sh[oj + i] = E;
        Eg[i * SL + j] = E;
        if (acc > 3.5e19f || acc < 3e-16f) red[fidx] = fmaxf(acc, 1e-30f);
      }
    }
    __syncthreads();
    float fl = red[fidx];
    if (fl != 0.f) {                      // uniform branch
      float dc = (__logf(fl) + 8.0f) / (float)w;   // recenter dev to ~-8
      rescaleE(tid, dc, w, Eg, sh);
      __syncthreads();
      if (tid == 0) red[fidx] = 0.f;
      __syncthreads();
    }
  }
}

// Outside widths w0 down to w1 (gather): g = E_pq * (sum E[q,j]H[p,j] + sum E[i,p]H[i,q]).
template <int G>
__device__ __forceinline__ void outsideB(int w0, int w1, int tid,
    const float* __restrict__ sc, float* __restrict__ gOut,
    const float* __restrict__ Eg, float* __restrict__ Hg,
    float* __restrict__ HTg, const float* __restrict__ sh) {
  constexpr int LG = (G == 4) ? 2 : (G == 8) ? 3 : (G == 16) ? 4 : (G == 32) ? 5 : 6;
  const int c = tid >> LG, lig = tid & (G - 1);
  for (int w = w0; w >= w1; --w) {
    if (c < SL - w) {
      const int p = c, q = p + w;
      float a0 = 0.f, a1 = 0.f;
      const float* er = Eg + q * SL;      // right parents (p,j), j>q
      const float* hr = Hg + p * SL;
      for (int s4 = ((q + 1) & ~3) + 4 * lig; s4 < SL; s4 += 4 * G) {
        float4 a = *(const float4*)(er + s4);
        float4 bv = *(const float4*)(hr + s4);
        a0 = fmaf(a.x, bv.x, a0);
        a1 = fmaf(a.y, bv.y, a1);
        a0 = fmaf(a.z, bv.z, a0);
        a1 = fmaf(a.w, bv.w, a1);
      }
      if (p > 0) {                        // left parents (i,q), i<p
        const float* et = sh + rowOff(p); // E column p == LDS row p
        const float* ht = HTg + q * SL;
        for (int s4 = 4 * lig; s4 < p; s4 += 4 * G) {
          float4 a = *(const float4*)(et + s4);
          float4 bv = *(const float4*)(ht + s4);
          a0 = fmaf(a.x, bv.x, a0);
          a1 = fmaf(a.y, bv.y, a1);
          a0 = fmaf(a.z, bv.z, a0);
          a1 = fmaf(a.w, bv.w, a1);
        }
      }
      float acc = grpSum<G>(a0 + a1);
      if (lig == 0) {
        float Epq = sh[rowOff(q) + p];
        gOut[p * SL + q] = Epq * acc;
        float H = acc * __expf(sc[p * SL + q]);
        Hg[p * SL + q] = H;
        HTg[q * SL + p] = H;
      }
    }
    __syncthreads();
  }
}

__global__ __launch_bounds__(NT) void cyk_exp(
    const float* __restrict__ scores, float* __restrict__ out,
    float* __restrict__ ws) {
  extern __shared__ float sh[];
  float* red = sh + LDSF;
  const int b = blockIdx.x;
  const int tid = threadIdx.x;
  const int lane = tid & 63;
  const int wave = tid >> 6;
  const size_t P = (size_t)SL * SL;
  const float* sc = scores + (size_t)b * P;
  float* g   = out + (size_t)b * P;
  float* Eg  = ws + (size_t)b * P;                 // E, row-major (lower tri = 0)
  float* Hg  = ws + (size_t)(BATCH + b) * P;       // H, row-major
  float* HTg = ws + (size_t)(2 * BATCH + b) * P;   // H transposed

  for (int idx = tid; idx < LDSF; idx += NT) sh[idx] = 0.f;
  if (tid < REDF) red[tid] = 0.f;
  __syncthreads();

  // width 1: store s = sc (log space for phase A)
  for (int i = tid; i < SL - 1; i += NT)
    sh[rowOff(i + 1) + i] = sc[i * SL + i + 1];
  __syncthreads();

  // ---- phase A: widths 2..W0, log space (exp per term; only ~4% of terms) ----
  {
    const int c4 = tid >> 2, lig = tid & 3;
    for (int w = 2; w <= W0; ++w) {
      if (c4 < SL - w) {
        const int i = c4, j = i + w;
        const int oj = rowOff(j);
        float m = -1e30f, sum = 0.f;
        for (int k = i + 1 + lig; k < j; k += 4) {
          float t = sh[rowOff(k) + i] + sh[oj + k];
          float nm = fmaxf(m, t);
          sum = sum * __expf(m - nm) + __expf(t - nm);
          m = nm;
        }
#pragma unroll
        for (int o = 2; o; o >>= 1) {
          float mo = __shfl_xor(m, o, 64);
          float so = __shfl_xor(sum, o, 64);
          float nm = fmaxf(m, mo);
          sum = sum * __expf(m - nm) + so * __expf(mo - nm);
          m = nm;
        }
        if (lig == 0) sh[oj + i] = sc[i * SL + j] + m + __logf(sum);
      }
      __syncthreads();
    }
  }

  // ---- calibrate c = max(s at width W0)/W0 ----
  {
    int idx = tid < SL - W0 ? tid : SL - W0 - 1;
    float v = sh[rowOff(idx + W0) + idx];
#pragma unroll
    for (int o = 32; o; o >>= 1) v = fmaxf(v, __shfl_xor(v, o, 64));
    if (lane == 0) red[wave] = v;
  }
  __syncthreads();
  float cc;
  {
    float mx = red[0];
#pragma unroll
    for (int t = 1; t < 16; ++t) mx = fmaxf(mx, red[t]);
    cc = mx / (float)W0;
  }

  // ---- convert widths 1..W0 to E-space; fill Eg ----
  for (int w = 1; w <= W0; ++w) {
    for (int i = tid; i < SL - w; i += NT) {
      int j = i + w;
      int o = rowOff(j) + i;
      float E = __expf(sh[o] - cc * (float)w);
      sh[o] = E;
      Eg[i * SL + j] = E;
    }
  }
  __syncthreads();

  // ---- phase B inside: pure fma dot products ----
  insideB<4>(W0 + 1, 127, tid, sc, Eg, sh, red);
  insideB<8>(128, 191, tid, sc, Eg, sh, red);
  insideB<16>(192, 223, tid, sc, Eg, sh, red);
  insideB<32>(224, 239, tid, sc, Eg, sh, red);
  insideB<64>(240, 255, tid, sc, Eg, sh, red);

  // ---- root: g=1, H_root = exp(sc)/E ----
  if (tid == 0) {
    g[0 * SL + (SL - 1)] = 1.0f;
    float Er = sh[rowOff(SL - 1) + 0];
    float Hr = (Er > 0.f) ? __expf(sc[0 * SL + (SL - 1)]) / Er : 0.f;
    Hg[0 * SL + (SL - 1)] = Hr;
    HTg[(SL - 1) * SL + 0] = Hr;
  }
  __syncthreads();

  // ---- outside: pure fma gathers ----
  outsideB<64>(254, 240, tid, sc, g, Eg, Hg, HTg, sh);
  outsideB<32>(239, 224, tid, sc, g, Eg, Hg, HTg, sh);
  outsideB<16>(223, 192, tid, sc, g, Eg, Hg, HTg, sh);
  outsideB<8>(191, 128, tid, sc, g, Eg, Hg, HTg, sh);
  outsideB<4>(127, 1, tid, sc, g, Eg, Hg, HTg, sh);
}

// ---------------- fallback: v2 global-memory kernel (proven, no transpose) ----
__device__ __forceinline__ float grpMaxR(float v, int G) {
#pragma unroll
  for (int o = 32; o; o >>= 1)
    if (o < G) v = fmaxf(v, __shfl_xor(v, o, 64));
  return v;
}
__device__ __forceinline__ float grpSumR(float v, int G) {
#pragma unroll
  for (int o = 32; o; o >>= 1)
    if (o < G) v += __shfl_xor(v, o, 64);
  return v;
}

__global__ __launch_bounds__(NT) void cyk_io_fb(
    const float* __restrict__ scores, float* __restrict__ out,
    float* __restrict__ ws) {
  const int b = blockIdx.x;
  const int tid = threadIdx.x;
  const size_t P = (size_t)SL * SL;
  const float* sc = scores + (size_t)b * P;
  float* g = out + (size_t)b * P;
  float* s = ws + (size_t)b * P;
  float* l = ws + (size_t)(BATCH + b) * P;

  for (int i = tid; i < SL - 1; i += NT) {
    s[i * SL + i + 1] = sc[i * SL + i + 1];
    l[i * SL + i + 1] = 0.f;
  }
  __syncthreads();

  for (int w = 2; w < SL; ++w) {
    const int cells = SL - w;
    int G = NT / cells;
    G = (G >= 64) ? 64 : (1 << (31 - __clz(G)));
    const int lg = 31 - __clz(G);
    const int c = tid >> lg;
    const int lig = tid & (G - 1);
    if (c < cells) {
      const int i = c, j = i + w;
      const float* srow = s + i * SL;
      float m = -INFINITY;
      for (int k = i + 1 + lig; k < j; k += G)
        m = fmaxf(m, srow[k] + s[k * SL + j]);
      m = grpMaxR(m, G);
      float sum = 0.f;
      for (int k = i + 1 + lig; k < j; k += G)
        sum += __expf(srow[k] + s[k * SL + j] - m);
      sum = grpSumR(sum, G);
      if (lig == 0) {
        const float lse = m + __logf(sum);
        s[i * SL + j] = sc[i * SL + j] + lse;
        l[i * SL + j] = lse;
      }
    }
    __syncthreads();
  }

  if (tid == 0) g[0 * SL + (SL - 1)] = 1.0f;
  __syncthreads();

  for (int w = SL - 2; w >= 1; --w) {
    const int cells = SL - w;
    int G = NT / cells;
    G = (G >= 64) ? 64 : (1 << (31 - __clz(G)));
    const int lg = 31 - __clz(G);
    const int c = tid >> lg;
    const int lig = tid & (G - 1);
    if (c < cells) {
      const int p = c, q = p + w;
      const float spq = s[p * SL + q];
      const int TR = SL - 1 - q;
      const int T = TR + p;
      float acc = 0.f;
      for (int t = lig; t < T; t += G) {
        if (t < TR) {
          const int j = q + 1 + t;
          acc += g[p * SL + j] * __expf(spq + s[q * SL + j] - l[p * SL + j]);
        } else {
          const int i = t - TR;
          acc += g[i * SL + q] * __expf(s[i * SL + p] + spq - l[i * SL + q]);
        }
      }
      acc = grpSumR(acc, G);
      if (lig == 0) g[p * SL + q] = acc;
    }
    __syncthreads();
  }
}

extern "C" void kernel_launch(void* const* d_in, const int* in_sizes, int n_in,
                              void* d_out, int out_size, void* d_ws, size_t ws_size,
                              hipStream_t stream) {
  const float* scores = (const float*)d_in[0];
  // d_in[1] = mask: triu(k=1) broadcast -> lens == SL-1 always; unused.
  float* out = (float*)d_out;
  float* ws = (float*)d_ws;

  const size_t sq = (size_t)SL * SL * sizeof(float);       // 256 KB
  hipMemsetAsync(d_out, 0, (size_t)BATCH * sq, stream);

  int dev = 0;
  hipGetDevice(&dev);
  int maxShm = 0;
  hipDeviceGetAttribute(&maxShm, hipDeviceAttributeMaxSharedMemoryPerBlock, dev);
  (void)hipFuncSetAttribute(reinterpret_cast<const void*>(cyk_exp),
                            hipFuncAttributeMaxDynamicSharedMemorySize, LDSB);

  if (maxShm >= LDSB && ws_size >= (size_t)3 * BATCH * sq) {
    hipMemsetAsync(ws, 0, (size_t)3 * BATCH * sq, stream);  // E/H/HT guards = 0
    cyk_exp<<<BATCH, NT, LDSB, stream>>>(scores, out, ws);
  } else {
    cyk_io_fb<<<BATCH, NT, 0, stream>>>(scores, out, ws);
  }
}